// Round 13
// baseline (616.870 us; speedup 1.0000x reference)
//
#include <hip/hip_runtime.h>
#include <cstdint>
#include <cstddef>

// ---------------- problem constants ----------------
#define BB   8
#define LLEN 2048
#define DSZ  1024
#define FFN  4096
#define MROWS (BB*LLEN)   // 16384
#define EPSLN 1e-5f
#define WKV_C 64
#define WKV_S (LLEN/WKV_C)          // 32
#define WKV_STATES (BB*WKV_C*DSZ)   // 524288

typedef __bf16 bh8 __attribute__((ext_vector_type(8)));
typedef float  f32x4 __attribute__((ext_vector_type(4)));

__device__ __forceinline__ unsigned short f32_to_bf16(float f) {
  unsigned int u = __float_as_uint(f);
  u += 0x7FFFu + ((u >> 16) & 1u);
  return (unsigned short)(u >> 16);
}
__device__ __forceinline__ float bf16_to_f32(unsigned short u) {
  return __uint_as_float(((unsigned int)u) << 16);
}
__device__ __forceinline__ float bf16_lo(unsigned int u) {
  return __uint_as_float(u << 16);
}
__device__ __forceinline__ float bf16_hi(unsigned int u) {
  return __uint_as_float(u & 0xFFFF0000u);
}
__device__ __forceinline__ unsigned int pack_bf16(float lo, float hi) {
  return (unsigned int)f32_to_bf16(lo) | ((unsigned int)f32_to_bf16(hi) << 16);
}
__device__ __forceinline__ float fexp(float x) { return __expf(x); }
__device__ __forceinline__ float frcp(float x) { return __builtin_amdgcn_rcpf(x); }

__device__ __forceinline__ void load_lds16(const void* g, void* l) {
  __builtin_amdgcn_global_load_lds((const __attribute__((address_space(1))) void*)g,
                                   (__attribute__((address_space(3))) void*)l, 16, 0, 0);
}

#define RAW_BAR() asm volatile("s_barrier" ::: "memory")
#define WAIT_VM4() asm volatile("s_waitcnt vmcnt(4)" ::: "memory")
#define WAIT_VM0() asm volatile("s_waitcnt vmcnt(0)" ::: "memory")

// ---------------- merged weight transpose + f32->bf16 (all 7 matrices, 1 launch) ----------------
struct TD { const float* s; unsigned short* d; int K; int N; };
struct TDs { TD t[7]; int base[8]; };

__global__ __launch_bounds__(256) void transpose_all(TDs td) {
  __shared__ float tile[32][33];
  int bid = blockIdx.x;
  int i = 0;
#pragma unroll
  for (int j = 1; j < 7; ++j) if (bid >= td.base[j]) i = j;
  const float* W = td.t[i].s;
  unsigned short* Wt = td.t[i].d;
  int K = td.t[i].K, N = td.t[i].N;
  int lid = bid - td.base[i];
  int gx = N >> 5;
  int n0 = (lid % gx) * 32, k0 = (lid / gx) * 32;
  int tx = threadIdx.x & 31, ty = threadIdx.x >> 5;   // 32x8
#pragma unroll
  for (int j = 0; j < 32; j += 8)
    tile[ty + j][tx] = W[(size_t)(k0 + ty + j) * N + n0 + tx];
  __syncthreads();
#pragma unroll
  for (int j = 0; j < 32; j += 8)
    Wt[(size_t)(n0 + ty + j) * K + k0 + tx] = f32_to_bf16(tile[tx][ty + j]);
}

// ---------------- fused LayerNorm + time-shift mix (att) ----------------
__global__ __launch_bounds__(256) void lnmix_att(const float* __restrict__ x,
                                                 const float* __restrict__ g,
                                                 const float* __restrict__ bb,
                                                 const float* __restrict__ mk,
                                                 const float* __restrict__ mv,
                                                 const float* __restrict__ mr,
                                                 unsigned short* __restrict__ xk,
                                                 unsigned short* __restrict__ xv,
                                                 unsigned short* __restrict__ xr) {
  int row = blockIdx.x;
  int t = row & (LLEN - 1);
  int tid = threadIdx.x;
  float4 vc = ((const float4*)(x + (size_t)row * DSZ))[tid];
  float4 vp = make_float4(0.f, 0.f, 0.f, 0.f);
  if (t > 0) vp = ((const float4*)(x + (size_t)(row - 1) * DSZ))[tid];
  float sc = vc.x + vc.y + vc.z + vc.w;
  float qc = vc.x * vc.x + vc.y * vc.y + vc.z * vc.z + vc.w * vc.w;
  float sp = vp.x + vp.y + vp.z + vp.w;
  float qp = vp.x * vp.x + vp.y * vp.y + vp.z * vp.z + vp.w * vp.w;
#pragma unroll
  for (int off = 32; off; off >>= 1) {
    sc += __shfl_down(sc, off); qc += __shfl_down(qc, off);
    sp += __shfl_down(sp, off); qp += __shfl_down(qp, off);
  }
  __shared__ float red[16];
  int lane = tid & 63, w = tid >> 6;
  if (lane == 0) { red[w] = sc; red[4 + w] = qc; red[8 + w] = sp; red[12 + w] = qp; }
  __syncthreads();
  if (tid < 4) red[tid * 4] = red[tid * 4] + red[tid * 4 + 1] + red[tid * 4 + 2] + red[tid * 4 + 3];
  __syncthreads();
  const float invD = 1.f / DSZ;
  float mc = red[0] * invD, rc = rsqrtf(red[4] * invD - mc * mc + EPSLN);
  float mp = red[8] * invD, rp = rsqrtf(red[12] * invD - mp * mp + EPSLN);
  float4 G = ((const float4*)g)[tid], Bv = ((const float4*)bb)[tid];
  float c[4] = { vc.x, vc.y, vc.z, vc.w };
  float p[4] = { vp.x, vp.y, vp.z, vp.w };
  float Ga[4] = { G.x, G.y, G.z, G.w };
  float Ba[4] = { Bv.x, Bv.y, Bv.z, Bv.w };
  float4 K = ((const float4*)mk)[tid];
  float4 V = ((const float4*)mv)[tid];
  float4 R = ((const float4*)mr)[tid];
  float Ka[4] = { K.x, K.y, K.z, K.w };
  float Va[4] = { V.x, V.y, V.z, V.w };
  float Ra[4] = { R.x, R.y, R.z, R.w };
  ushort4 ok, ov, orr;
  unsigned short* okp = &ok.x; unsigned short* ovp = &ov.x; unsigned short* orp = &orr.x;
#pragma unroll
  for (int e = 0; e < 4; ++e) {
    float hc = (c[e] - mc) * rc * Ga[e] + Ba[e];
    float hp = (t > 0) ? (p[e] - mp) * rp * Ga[e] + Ba[e] : 0.f;
    okp[e] = f32_to_bf16(hc * Ka[e] + hp * (1.f - Ka[e]));
    ovp[e] = f32_to_bf16(hc * Va[e] + hp * (1.f - Va[e]));
    orp[e] = f32_to_bf16(hc * Ra[e] + hp * (1.f - Ra[e]));
  }
  size_t e4 = (size_t)row * DSZ + tid * 4;
  *(ushort4*)(xk + e4) = ok;
  *(ushort4*)(xv + e4) = ov;
  *(ushort4*)(xr + e4) = orr;
}

// ---------------- fused LayerNorm + time-shift mix (ffn) ----------------
__global__ __launch_bounds__(256) void lnmix_ffn(const float* __restrict__ x,
                                                 const float* __restrict__ g,
                                                 const float* __restrict__ bb,
                                                 const float* __restrict__ mk,
                                                 const float* __restrict__ mr,
                                                 unsigned short* __restrict__ xk,
                                                 unsigned short* __restrict__ xr) {
  int row = blockIdx.x;
  int t = row & (LLEN - 1);
  int tid = threadIdx.x;
  float4 vc = ((const float4*)(x + (size_t)row * DSZ))[tid];
  float4 vp = make_float4(0.f, 0.f, 0.f, 0.f);
  if (t > 0) vp = ((const float4*)(x + (size_t)(row - 1) * DSZ))[tid];
  float sc = vc.x + vc.y + vc.z + vc.w;
  float qc = vc.x * vc.x + vc.y * vc.y + vc.z * vc.z + vc.w * vc.w;
  float sp = vp.x + vp.y + vp.z + vp.w;
  float qp = vp.x * vp.x + vp.y * vp.y + vp.z * vp.z + vp.w * vp.w;
#pragma unroll
  for (int off = 32; off; off >>= 1) {
    sc += __shfl_down(sc, off); qc += __shfl_down(qc, off);
    sp += __shfl_down(sp, off); qp += __shfl_down(qp, off);
  }
  __shared__ float red[16];
  int lane = tid & 63, w = tid >> 6;
  if (lane == 0) { red[w] = sc; red[4 + w] = qc; red[8 + w] = sp; red[12 + w] = qp; }
  __syncthreads();
  if (tid < 4) red[tid * 4] = red[tid * 4] + red[tid * 4 + 1] + red[tid * 4 + 2] + red[tid * 4 + 3];
  __syncthreads();
  const float invD = 1.f / DSZ;
  float mc = red[0] * invD, rc = rsqrtf(red[4] * invD - mc * mc + EPSLN);
  float mp = red[8] * invD, rp = rsqrtf(red[12] * invD - mp * mp + EPSLN);
  float4 G = ((const float4*)g)[tid], Bv = ((const float4*)bb)[tid];
  float c[4] = { vc.x, vc.y, vc.z, vc.w };
  float p[4] = { vp.x, vp.y, vp.z, vp.w };
  float Ga[4] = { G.x, G.y, G.z, G.w };
  float Ba[4] = { Bv.x, Bv.y, Bv.z, Bv.w };
  float4 K = ((const float4*)mk)[tid];
  float4 R = ((const float4*)mr)[tid];
  float Ka[4] = { K.x, K.y, K.z, K.w };
  float Ra[4] = { R.x, R.y, R.z, R.w };
  ushort4 ok, orr;
  unsigned short* okp = &ok.x; unsigned short* orp = &orr.x;
#pragma unroll
  for (int e = 0; e < 4; ++e) {
    float hc = (c[e] - mc) * rc * Ga[e] + Ba[e];
    float hp = (t > 0) ? (p[e] - mp) * rp * Ga[e] + Ba[e] : 0.f;
    okp[e] = f32_to_bf16(hc * Ka[e] + hp * (1.f - Ka[e]));
    orp[e] = f32_to_bf16(hc * Ra[e] + hp * (1.f - Ra[e]));
  }
  size_t e4 = (size_t)row * DSZ + tid * 4;
  *(ushort4*)(xk + e4) = ok;
  *(ushort4*)(xr + e4) = orr;
}

// ---------------- WKV chunked scan (2 channels per thread, C=64, fast-math) ----------------
__global__ __launch_bounds__(256) void wkv_pass1(const unsigned int* __restrict__ kk2,
                                                 const unsigned int* __restrict__ vv2,
                                                 const float* __restrict__ td,
                                                 float* __restrict__ sP,
                                                 float* __restrict__ sQ,
                                                 float* __restrict__ sO) {
  int gid = blockIdx.x * 256 + threadIdx.x;       // 0 .. WKV_STATES/2-1
  int d2 = gid & 511;
  int bc = gid >> 9;
  int c  = bc & (WKV_C - 1);
  int b  = bc >> 6;
  int d0 = d2 * 2;
  float w0 = -fexp(td[d0]), w1 = -fexp(td[d0 + 1]);
  size_t base = ((size_t)b * LLEN + (size_t)c * WKV_S) * 512 + d2;   // uint units
  float p0 = 0.f, q0 = 0.f, o0 = -1e38f;
  float p1 = 0.f, q1 = 0.f, o1 = -1e38f;
  unsigned int kc = kk2[base], vc = vv2[base];
  unsigned int kA = 0, vA = 0, kB = 0, vB = 0;
  if (WKV_S > 1) { kA = kk2[base + 512]; vA = vv2[base + 512]; }
  for (int t = 0; t < WKV_S; ++t) {
    if (t + 2 < WKV_S) {
      size_t nxt = base + (size_t)(t + 2) * 512;
      kB = kk2[nxt]; vB = vv2[nxt];
    } else { kB = 0; vB = 0; }
    {
      float kt = bf16_lo(kc), vt = bf16_lo(vc);
      float ow = o0 + w0;
      float no2 = fmaxf(ow, kt);
      float A2 = fexp(ow - no2), B2 = fexp(kt - no2);
      p0 = A2 * p0 + B2 * vt; q0 = A2 * q0 + B2; o0 = no2;
    }
    {
      float kt = bf16_hi(kc), vt = bf16_hi(vc);
      float ow = o1 + w1;
      float no2 = fmaxf(ow, kt);
      float A2 = fexp(ow - no2), B2 = fexp(kt - no2);
      p1 = A2 * p1 + B2 * vt; q1 = A2 * q1 + B2; o1 = no2;
    }
    kc = kA; vc = vA; kA = kB; vA = vB;
  }
  int sidx = (bc << 10) + d0;
  sP[sidx] = p0; sP[sidx + 1] = p1;
  sQ[sidx] = q0; sQ[sidx + 1] = q1;
  sO[sidx] = o0; sO[sidx + 1] = o1;
}

__global__ __launch_bounds__(256) void wkv_combine(const float* __restrict__ sP,
                                                   const float* __restrict__ sQ,
                                                   const float* __restrict__ sO,
                                                   const float* __restrict__ td,
                                                   float* __restrict__ pP,
                                                   float* __restrict__ pQ,
                                                   float* __restrict__ pO) {
  int gid = blockIdx.x * 256 + threadIdx.x;
  int d = gid & (DSZ - 1);
  int b = gid >> 10;
  float w = -fexp(td[d]);
  float Sw = (float)WKV_S * w;
  float p = 0.f, q = 0.f, o = -1e38f;
  for (int c = 0; c < WKV_C; ++c) {
    size_t idx = (((size_t)b * WKV_C + c) << 10) + d;
    pP[idx] = p; pQ[idx] = q; pO[idx] = o;
    float lp = sP[idx], lq = sQ[idx], lo = sO[idx];
    float oin = o + Sw;
    float no  = fmaxf(oin, lo);
    float Ai  = fexp(oin - no);
    float Al  = fexp(lo - no);
    p = Ai * p + Al * lp;
    q = Ai * q + Al * lq;
    o = no;
  }
}

__global__ __launch_bounds__(256) void wkv_pass3(const unsigned int* __restrict__ kk2,
                                                 const unsigned int* __restrict__ vv2,
                                                 const unsigned int* __restrict__ rr2,
                                                 const float* __restrict__ td,
                                                 const float* __restrict__ tf,
                                                 const float* __restrict__ pP,
                                                 const float* __restrict__ pQ,
                                                 const float* __restrict__ pO,
                                                 unsigned int* __restrict__ rw2) {
  int gid = blockIdx.x * 256 + threadIdx.x;
  int d2 = gid & 511;
  int bc = gid >> 9;
  int c  = bc & (WKV_C - 1);
  int b  = bc >> 6;
  int d0 = d2 * 2;
  float w0 = -fexp(td[d0]), w1 = -fexp(td[d0 + 1]);
  float u0 = tf[d0], u1 = tf[d0 + 1];
  int sidx = (bc << 10) + d0;
  float p0 = pP[sidx], q0 = pQ[sidx], o0 = pO[sidx];
  float p1 = pP[sidx + 1], q1 = pQ[sidx + 1], o1 = pO[sidx + 1];
  size_t base = ((size_t)b * LLEN + (size_t)c * WKV_S) * 512 + d2;
  unsigned int kc = kk2[base], vc = vv2[base], rc = rr2[base];
  unsigned int kA = 0, vA = 0, rA = 0, kB = 0, vB = 0, rB = 0;
  if (WKV_S > 1) { kA = kk2[base + 512]; vA = vv2[base + 512]; rA = rr2[base + 512]; }
  for (int t = 0; t < WKV_S; ++t) {
    if (t + 2 < WKV_S) {
      size_t nxt = base + (size_t)(t + 2) * 512;
      kB = kk2[nxt]; vB = vv2[nxt]; rB = rr2[nxt];
    } else { kB = 0; vB = 0; rB = 0; }
    float out0, out1;
    {
      float kt = bf16_lo(kc), vt = bf16_lo(vc);
      float uk = u0 + kt;
      float no = fmaxf(o0, uk);
      float A  = fexp(o0 - no), Bc = fexp(uk - no);
      out0 = (A * p0 + Bc * vt) * frcp(A * q0 + Bc);
      float ow = o0 + w0;
      float no2 = fmaxf(ow, kt);
      float A2 = fexp(ow - no2), B2 = fexp(kt - no2);
      p0 = A2 * p0 + B2 * vt; q0 = A2 * q0 + B2; o0 = no2;
    }
    {
      float kt = bf16_hi(kc), vt = bf16_hi(vc);
      float uk = u1 + kt;
      float no = fmaxf(o1, uk);
      float A  = fexp(o1 - no), Bc = fexp(uk - no);
      out1 = (A * p1 + Bc * vt) * frcp(A * q1 + Bc);
      float ow = o1 + w1;
      float no2 = fmaxf(ow, kt);
      float A2 = fexp(ow - no2), B2 = fexp(kt - no2);
      p1 = A2 * p1 + B2 * vt; q1 = A2 * q1 + B2; o1 = no2;
    }
    rw2[base + (size_t)t * 512] = pack_bf16(bf16_lo(rc) * out0, bf16_hi(rc) * out1);
    kc = kA; vc = vA; rc = rA; kA = kB; vA = vB; rA = rB;
  }
}

// ============ 256x256 bf16 MFMA GEMM, 2-phase, read-free ph2: C = A * Bt^T ============
// 512 threads = 8 waves (2M x 4N), BK=64, LDS 128 KiB dbuf. 2 barriers per K-tile.
// ph1: ALL 24 frag reads (a03,b01 -> Q1 waits ~12; b23,a47 drain UNDER Q1/Q2);
//      stage A0A1[t+1]->bufn; Q1,Q2; bar#1.
// ph2: stage B0B1[t+2]->buf (b-reads drained via Q1/Q2 reg-deps before bar#1);
//      Q3,Q4 with ZERO lgkm waits (a47 drained under ph1 MFMA); vmcnt(4); bar#2.
// vmcnt queue at boundary: B[t+1](4)+A[t+1](4)+B[t+2](4) -> vmcnt(4) retires tile t+1.
// a47 reads of buf drained via Q3/Q4 reg-deps before bar#2; buf A-region next written
// in ph1 of t+2 (two barriers later) -> no WAR race.
#define KTILE_BODY(T)                                                             \
  {                                                                               \
    const int buf  = ((T) & 1) << 15;                                             \
    const int bufn = buf ^ 32768;                                                 \
    bh8 a03[4][2], a47[4][2], b01[2][2], b23[2][2];                               \
    /* ---- phase 1: all reads + A-stage + Q1,Q2 ---- */                          \
    _Pragma("unroll")                                                             \
    for (int mi = 0; mi < 4; ++mi) {                                              \
      a03[mi][0] = *(const bh8*)(smA + buf + aRow + mi * 2048 + sw0);             \
      a03[mi][1] = *(const bh8*)(smA + buf + aRow + mi * 2048 + sw1);             \
    }                                                                             \
    _Pragma("unroll")                                                             \
    for (int nj = 0; nj < 2; ++nj) {                                              \
      b01[nj][0] = *(const bh8*)(smB + buf + bRow + nj * 2048 + sw0);             \
      b01[nj][1] = *(const bh8*)(smB + buf + bRow + nj * 2048 + sw1);             \
    }                                                                             \
    if ((T) + 1 < nk) {                                                           \
      load_lds16(pA0  + 64, smA + bufn + ldsW);                                   \
      load_lds16(pA0b + 64, smA + bufn + 1024 + ldsW);                            \
      load_lds16(pA1  + 64, smA + bufn + 16384 + ldsW);                           \
      load_lds16(pA1b + 64, smA + bufn + 16384 + 1024 + ldsW);                    \
    }                                                                             \
    _Pragma("unroll")                                                             \
    for (int nj = 0; nj < 2; ++nj) {                                              \
      b23[nj][0] = *(const bh8*)(smB + buf + bRow + (nj + 2) * 2048 + sw0);       \
      b23[nj][1] = *(const bh8*)(smB + buf + bRow + (nj + 2) * 2048 + sw1);       \
    }                                                                             \
    _Pragma("unroll")                                                             \
    for (int mi = 0; mi < 4; ++mi) {                                              \
      a47[mi][0] = *(const bh8*)(smA + buf + aRow + (mi + 4) * 2048 + sw0);       \
      a47[mi][1] = *(const bh8*)(smA + buf + aRow + (mi + 4) * 2048 + sw1);       \
    }                                                                             \
    __builtin_amdgcn_s_setprio(1);                                                \
    _Pragma("unroll")                                                             \
    for (int mi = 0; mi < 4; ++mi)                                                \
      _Pragma("unroll")                                                           \
      for (int nj = 0; nj < 2; ++nj) {                                            \
        acc[mi][nj] = __builtin_amdgcn_mfma_f32_16x16x32_bf16(a03[mi][0], b01[nj][0], acc[mi][nj], 0, 0, 0); \
        acc[mi][nj] = __builtin_amdgcn_mfma_f32_16x16x32_bf16(a03[mi][1], b01[nj][1], acc[mi][nj], 0, 0, 0); \
      }                                                                           \
    _Pragma("unroll")                                                             \
    for (int mi = 0; mi < 4; ++mi)                                                \
      _Pragma("unroll")                                                           \
      for (int nj = 0; nj < 2; ++nj) {                                            \
        acc[mi][nj + 2] = __builtin_amdgcn_mfma_f32_16x16x32_bf16(a03[mi][0], b23[nj][0], acc[mi][nj + 2], 0, 0, 0); \
        acc[mi][nj + 2] = __builtin_amdgcn_mfma_f32_16x16x32_bf16(a03[mi][1], b23[nj][1], acc[mi][nj + 2], 0, 0, 0); \
      }                                                                           \
    __builtin_amdgcn_s_setprio(0);                                                \
    RAW_BAR();                                                                    \
    /* ---- phase 2: B-stage + Q3,Q4 (no reads, no lgkm waits) ---- */            \
    if ((T) + 2 < nk) {                                                           \
      load_lds16(pB0  + 128, smB + buf + ldsW);                                   \
      load_lds16(pB0b + 128, smB + buf + 1024 + ldsW);                            \
      load_lds16(pB1  + 128, smB + buf + 16384 + ldsW);                           \
      load_lds16(pB1b + 128, smB + buf + 16384 + 1024 + ldsW);                    \
    }                                                                             \
    __builtin_amdgcn_s_setprio(1);                                                \
    _Pragma("unroll")                                                             \
    for (int mi = 0; mi < 4; ++mi)                                                \
      _Pragma("unroll")                                                           \
      for (int nj = 0; nj < 2; ++nj) {                                            \
        acc[mi + 4][nj] = __builtin_amdgcn_mfma_f32_16x16x32_bf16(a47[mi][0], b01[nj][0], acc[mi + 4][nj], 0, 0, 0); \
        acc[mi + 4][nj] = __builtin_amdgcn_mfma_f32_16x16x32_bf16(a47[mi][1], b01[nj][1], acc[mi + 4][nj], 0, 0, 0); \
      }                                                                           \
    _Pragma("unroll")                                                             \
    for (int mi = 0; mi < 4; ++mi)                                                \
      _Pragma("unroll")                                                           \
      for (int nj = 0; nj < 2; ++nj) {                                            \
        acc[mi + 4][nj + 2] = __builtin_amdgcn_mfma_f32_16x16x32_bf16(a47[mi][0], b23[nj][0], acc[mi + 4][nj + 2], 0, 0, 0); \
        acc[mi + 4][nj + 2] = __builtin_amdgcn_mfma_f32_16x16x32_bf16(a47[mi][1], b23[nj][1], acc[mi + 4][nj + 2], 0, 0, 0); \
      }                                                                           \
    __builtin_amdgcn_s_setprio(0);                                                \
    if ((T) + 2 < nk) { WAIT_VM4(); } else { WAIT_VM0(); }                        \
    RAW_BAR();                                                                    \
  }

// common body: setup + prologue + K-loop
#define GEMM_SETUP(AB, BB_, KD)                                                   \
  const unsigned short* Ab = (AB);                                                \
  const unsigned short* Bb = (BB_);                                               \
  const int nk = (KD) >> 6;                                                       \
  const int r15 = lane & 15;                                                      \
  const int sw0 = ((((lane >> 4)    ) ^ (lane & 7)) << 4);                        \
  const int sw1 = (((4 | (lane >> 4)) ^ (lane & 7)) << 4);                        \
  const int aRow = wr * 16384 + r15 * 128;                                        \
  const int bRow = wc * 8192  + r15 * 128;                                        \
  const int ldsW = wid * 2048 + lane * 16;                                        \
  const int grow = lane >> 3;                                                     \
  const int colS = (((lane & 7) ^ grow) << 3);                                    \
  const unsigned short* pA0  = Ab + (size_t)(wid * 16 + grow) * (KD) + colS;      \
  const unsigned short* pA0b = pA0 + (size_t)8 * (KD);                            \
  const unsigned short* pA1  = pA0 + (size_t)128 * (KD);                          \
  const unsigned short* pA1b = pA1 + (size_t)8 * (KD);                            \
  const unsigned short* pB0  = Bb + (size_t)(wid * 16 + grow) * (KD) + colS;      \
  const unsigned short* pB0b = pB0 + (size_t)8 * (KD);                            \
  const unsigned short* pB1  = pB0 + (size_t)128 * (KD);                          \
  const unsigned short* pB1b = pB1 + (size_t)8 * (KD);                            \
  f32x4 acc[8][4];                                                                \
  _Pragma("unroll")                                                               \
  for (int i = 0; i < 8; ++i)                                                     \
    _Pragma("unroll")                                                             \
    for (int j = 0; j < 4; ++j)                                                   \
      _Pragma("unroll")                                                           \
      for (int e = 0; e < 4; ++e) acc[i][j][e] = 0.f;                             \
  /* prologue: tile0 A+B (8 loads), then B[1] (4); vmcnt(4) retires tile0 */      \
  load_lds16(pA0,       smA + ldsW);                                              \
  load_lds16(pA0b,      smA + 1024 + ldsW);                                       \
  load_lds16(pA1,       smA + 16384 + ldsW);                                      \
  load_lds16(pA1b,      smA + 16384 + 1024 + ldsW);                               \
  load_lds16(pB0,       smB + ldsW);                                              \
  load_lds16(pB0b,      smB + 1024 + ldsW);                                       \
  load_lds16(pB1,       smB + 16384 + ldsW);                                      \
  load_lds16(pB1b,      smB + 16384 + 1024 + ldsW);                               \
  if (nk > 1) {                                                                   \
    load_lds16(pB0  + 64, smB + 32768 + ldsW);                                    \
    load_lds16(pB0b + 64, smB + 32768 + 1024 + ldsW);                             \
    load_lds16(pB1  + 64, smB + 32768 + 16384 + ldsW);                            \
    load_lds16(pB1b + 64, smB + 32768 + 16384 + 1024 + ldsW);                     \
    WAIT_VM4();                                                                   \
  } else {                                                                        \
    WAIT_VM0();                                                                   \
  }                                                                               \
  RAW_BAR();                                                                      \
  for (int tb = 0; tb < nk; ++tb) {                                               \
    KTILE_BODY(tb)                                                                \
    pA0 += 64; pA0b += 64; pA1 += 64; pA1b += 64;                                 \
    pB0 += 64; pB0b += 64; pB1 += 64; pB1b += 64;                                 \
  }

template <int EPI>
__global__ __launch_bounds__(512, 2) void gemm256(const unsigned short* __restrict__ A,
                                                  const unsigned short* __restrict__ Bt,
                                                  float* __restrict__ C,
                                                  unsigned short* __restrict__ Cbf,
                                                  const float* __restrict__ aux1,
                                                  const unsigned short* __restrict__ aux2b,
                                                  int M, int N, int K) {
  extern __shared__ unsigned char sm[];            // 131072 bytes
  unsigned char* smA = sm;
  unsigned char* smB = sm + 65536;
  const int tid  = threadIdx.x;
  const int lane = tid & 63;
  const int wid  = tid >> 6;
  const int wr   = wid >> 2;
  const int wc   = wid & 3;
  int nwg = gridDim.x;
  int gx  = N >> 8;
  int wg  = blockIdx.x;
  int swzid = ((nwg & 7) == 0) ? ((wg & 7) * (nwg >> 3) + (wg >> 3)) : wg;
  int bn = swzid % gx, bm = swzid / gx;

  GEMM_SETUP(A + (size_t)bm * 256 * K, Bt + (size_t)bn * 256 * K, K)

  const int r4 = (lane >> 4) * 4, cn = lane & 15;
#pragma unroll
  for (int mi = 0; mi < 8; ++mi) {
#pragma unroll
    for (int nj = 0; nj < 4; ++nj) {
      int col = bn * 256 + wc * 64 + nj * 16 + cn;
#pragma unroll
      for (int e = 0; e < 4; ++e) {
        int row = bm * 256 + wr * 128 + mi * 16 + r4 + e;
        size_t idx = (size_t)row * N + col;
        float val = acc[mi][nj][e];
        if (EPI == 0) {
          Cbf[idx] = f32_to_bf16(val);
        } else if (EPI == 1) {
          Cbf[idx] = f32_to_bf16(frcp(1.f + fexp(-val)));
        } else if (EPI == 2) {
          C[idx] = aux1[idx] + val;
        } else if (EPI == 3) {
          float tt = val > 0.f ? val : 0.f;
          Cbf[idx] = f32_to_bf16(tt * tt);
        } else {
          C[idx] = aux1[idx] + bf16_to_f32(aux2b[idx]) * val;
        }
      }
    }
  }
}

// batched k/v/r projection: 3 independent M=16384 N=1024 K=1024 GEMMs in one launch.
__global__ __launch_bounds__(512, 2) void gemm256_kvr(const unsigned short* __restrict__ A0,
                                                      const unsigned short* __restrict__ A1,
                                                      const unsigned short* __restrict__ A2,
                                                      const unsigned short* __restrict__ B0w,
                                                      const unsigned short* __restrict__ B1w,
                                                      const unsigned short* __restrict__ B2w,
                                                      unsigned short* __restrict__ D0,
                                                      unsigned short* __restrict__ D1,
                                                      unsigned short* __restrict__ D2) {
  extern __shared__ unsigned char sm[];
  unsigned char* smA = sm;
  unsigned char* smB = sm + 65536;
  const int tid  = threadIdx.x;
  const int lane = tid & 63;
  const int wid  = tid >> 6;
  const int wr   = wid >> 2;
  const int wc   = wid & 3;
  int nwg = gridDim.x;                             // 768, %8==0
  int wg  = blockIdx.x;
  int swzid = (wg & 7) * (nwg >> 3) + (wg >> 3);
  int gsel  = swzid >> 8;                          // 0..2
  int local = swzid & 255;
  int bn = local & 3, bm = local >> 2;

  const unsigned short* Asel = (gsel == 0) ? A0 : (gsel == 1) ? A1 : A2;
  const unsigned short* Bsel = (gsel == 0) ? B0w : (gsel == 1) ? B1w : B2w;
  unsigned short*       Dsel = (gsel == 0) ? D0 : (gsel == 1) ? D1 : D2;

  GEMM_SETUP(Asel + (size_t)bm * 256 * DSZ, Bsel + (size_t)bn * 256 * DSZ, DSZ)

  const int r4 = (lane >> 4) * 4, cn = lane & 15;
  const bool sig = (gsel == 2);
#pragma unroll
  for (int mi = 0; mi < 8; ++mi) {
#pragma unroll
    for (int nj = 0; nj < 4; ++nj) {
      int col = bn * 256 + wc * 64 + nj * 16 + cn;
#pragma unroll
      for (int e = 0; e < 4; ++e) {
        int row = bm * 256 + wr * 128 + mi * 16 + r4 + e;
        size_t idx = (size_t)row * DSZ + col;
        float val = acc[mi][nj][e];
        Dsel[idx] = f32_to_bf16(sig ? frcp(1.f + fexp(-val)) : val);
      }
    }
  }
}

// ---------------- host launcher ----------------
extern "C" void kernel_launch(void* const* d_in, const int* in_sizes, int n_in,
                              void* d_out, int out_size, void* d_ws, size_t ws_size,
                              hipStream_t stream) {
  const float* x        = (const float*)d_in[0];
  const float* ln_att_g = (const float*)d_in[1];
  const float* ln_att_b = (const float*)d_in[2];
  const float* ln_ffn_g = (const float*)d_in[3];
  const float* ln_ffn_b = (const float*)d_in[4];
  const float* td       = (const float*)d_in[5];
  const float* tf       = (const float*)d_in[6];
  const float* amk      = (const float*)d_in[7];
  const float* amv      = (const float*)d_in[8];
  const float* amr      = (const float*)d_in[9];
  const float* att_wk   = (const float*)d_in[10];
  const float* att_wv   = (const float*)d_in[11];
  const float* att_wr   = (const float*)d_in[12];
  const float* att_wo   = (const float*)d_in[13];
  const float* fmk      = (const float*)d_in[14];
  const float* fmr      = (const float*)d_in[15];
  const float* ffn_wk   = (const float*)d_in[16];
  const float* ffn_wv   = (const float*)d_in[17];
  const float* ffn_wr   = (const float*)d_in[18];
  float* out = (float*)d_out;
  (void)in_sizes; (void)n_in; (void)out_size;

  const size_t WBYTES  = 4 * ((size_t)DSZ * DSZ * 2)
                       + (size_t)FFN * DSZ * 2
                       + (size_t)DSZ * FFN * 2
                       + (size_t)DSZ * DSZ * 2;
  const size_t BUF     = (size_t)MROWS * DSZ * 2;
  const size_t NEEDED  = WBYTES + 4 * BUF + 2 * BUF;
  if (ws_size < NEEDED) return;

  char* ws = (char*)d_ws;
  size_t off = 0;
  auto take = [&](size_t bytes) { char* p = ws + off; off += (bytes + 255) & ~(size_t)255; return p; };

  unsigned short* wkT  = (unsigned short*)take((size_t)DSZ * DSZ * 2);
  unsigned short* wvT  = (unsigned short*)take((size_t)DSZ * DSZ * 2);
  unsigned short* wrT  = (unsigned short*)take((size_t)DSZ * DSZ * 2);
  unsigned short* woT  = (unsigned short*)take((size_t)DSZ * DSZ * 2);
  unsigned short* fwkT = (unsigned short*)take((size_t)FFN * DSZ * 2);
  unsigned short* fwvT = (unsigned short*)take((size_t)DSZ * FFN * 2);
  unsigned short* fwrT = (unsigned short*)take((size_t)DSZ * DSZ * 2);
  unsigned short* bufA = (unsigned short*)take(BUF);
  unsigned short* bufB = (unsigned short*)take(BUF);
  unsigned short* bufC = (unsigned short*)take(BUF);
  unsigned short* bufD = (unsigned short*)take(BUF);
  char*           eReg = take(2 * BUF);
  unsigned short* kf = bufC;                       // spans C + D + E (ffn phase)
  unsigned short* vBuf = (unsigned short*)eReg;            // E[0:32M)  (att phase)
  unsigned short* rBuf = (unsigned short*)(eReg + BUF);    // E[32M:64M)

  // WKV state arrays live in bufA (xk dead after kvr GEMM): 6 x 2 MB
  float* sP = (float*)bufA;
  float* sQ = sP + WKV_STATES;
  float* sO = sQ + WKV_STATES;
  float* pP = sO + WKV_STATES;
  float* pQ = pP + WKV_STATES;
  float* pO = pQ + WKV_STATES;

  // ---- single merged transpose launch (7 matrices) ----
  TDs tds;
  tds.t[0] = { att_wk, wkT,  DSZ, DSZ };
  tds.t[1] = { att_wv, wvT,  DSZ, DSZ };
  tds.t[2] = { att_wr, wrT,  DSZ, DSZ };
  tds.t[3] = { att_wo, woT,  DSZ, DSZ };
  tds.t[4] = { ffn_wr, fwrT, DSZ, DSZ };
  tds.t[5] = { ffn_wk, fwkT, DSZ, FFN };
  tds.t[6] = { ffn_wv, fwvT, FFN, DSZ };
  int acc = 0;
  for (int i = 0; i < 7; ++i) {
    tds.base[i] = acc;
    acc += (tds.t[i].N >> 5) * (tds.t[i].K >> 5);
  }
  tds.base[7] = acc;                               // 13312
  transpose_all<<<acc, 256, 0, stream>>>(tds);

  const int LDSB = 131072;
  const int G1   = (MROWS / 256) * (DSZ / 256);    // 256 blocks
  const int G2   = (MROWS / 256) * (FFN / 256);    // 1024 blocks

  // --- attention branch ---
  lnmix_att<<<MROWS, 256, 0, stream>>>(x, ln_att_g, ln_att_b, amk, amv, amr, bufA, bufB, bufC);
  gemm256_kvr<<<3 * G1, 512, LDSB, stream>>>(bufA, bufB, bufC, wkT, wvT, wrT, bufD, vBuf, rBuf);
  wkv_pass1<<<(WKV_STATES / 2) / 256, 256, 0, stream>>>((const unsigned int*)bufD, (const unsigned int*)vBuf, td, sP, sQ, sO);
  wkv_combine<<<(BB * DSZ) / 256, 256, 0, stream>>>(sP, sQ, sO, td, pP, pQ, pO);
  wkv_pass3<<<(WKV_STATES / 2) / 256, 256, 0, stream>>>((const unsigned int*)bufD, (const unsigned int*)vBuf, (const unsigned int*)rBuf, td, tf, pP, pQ, pO, (unsigned int*)bufB);
  gemm256<2><<<G1, 512, LDSB, stream>>>(bufB, woT, out, nullptr, x, nullptr, MROWS, DSZ, DSZ);

  // --- ffn branch ---
  lnmix_ffn<<<MROWS, 256, 0, stream>>>(out, ln_ffn_g, ln_ffn_b, fmk, fmr, bufA, bufB);
  gemm256<3><<<G2, 512, LDSB, stream>>>(bufA, fwkT, nullptr, kf, nullptr, nullptr, MROWS, FFN, DSZ);
  gemm256<1><<<G1, 512, LDSB, stream>>>(bufB, fwrT, nullptr, bufA, nullptr, nullptr, MROWS, DSZ, DSZ);
  gemm256<4><<<G1, 512, LDSB, stream>>>(kf, fwvT, out, nullptr, out, bufA, MROWS, DSZ, FFN);
}

// Round 14
// 609.989 us; speedup vs baseline: 1.0113x; 1.0113x over previous
//
#include <hip/hip_runtime.h>
#include <cstdint>
#include <cstddef>

// ---------------- problem constants ----------------
#define BB   8
#define LLEN 2048
#define DSZ  1024
#define FFN  4096
#define MROWS (BB*LLEN)   // 16384
#define EPSLN 1e-5f
#define WKV_C 64
#define WKV_S (LLEN/WKV_C)          // 32
#define WKV_STATES (BB*WKV_C*DSZ)   // 524288

typedef __bf16 bh8 __attribute__((ext_vector_type(8)));
typedef float  f32x4 __attribute__((ext_vector_type(4)));

__device__ __forceinline__ unsigned short f32_to_bf16(float f) {
  unsigned int u = __float_as_uint(f);
  u += 0x7FFFu + ((u >> 16) & 1u);
  return (unsigned short)(u >> 16);
}
__device__ __forceinline__ float bf16_to_f32(unsigned short u) {
  return __uint_as_float(((unsigned int)u) << 16);
}
__device__ __forceinline__ float bf16_lo(unsigned int u) {
  return __uint_as_float(u << 16);
}
__device__ __forceinline__ float bf16_hi(unsigned int u) {
  return __uint_as_float(u & 0xFFFF0000u);
}
__device__ __forceinline__ unsigned int pack_bf16(float lo, float hi) {
  return (unsigned int)f32_to_bf16(lo) | ((unsigned int)f32_to_bf16(hi) << 16);
}
__device__ __forceinline__ float fexp(float x) { return __expf(x); }
__device__ __forceinline__ float frcp(float x) { return __builtin_amdgcn_rcpf(x); }

__device__ __forceinline__ void load_lds16(const void* g, void* l) {
  __builtin_amdgcn_global_load_lds((const __attribute__((address_space(1))) void*)g,
                                   (__attribute__((address_space(3))) void*)l, 16, 0, 0);
}

#define RAW_BAR() asm volatile("s_barrier" ::: "memory")
#define WAIT_VM4() asm volatile("s_waitcnt vmcnt(4)" ::: "memory")
#define WAIT_VM0() asm volatile("s_waitcnt vmcnt(0)" ::: "memory")

// ---------------- merged weight transpose + f32->bf16 (all 7 matrices, 1 launch) ----------------
struct TD { const float* s; unsigned short* d; int K; int N; };
struct TDs { TD t[7]; int base[8]; };

__global__ __launch_bounds__(256) void transpose_all(TDs td) {
  __shared__ float tile[32][33];
  int bid = blockIdx.x;
  int i = 0;
#pragma unroll
  for (int j = 1; j < 7; ++j) if (bid >= td.base[j]) i = j;
  const float* W = td.t[i].s;
  unsigned short* Wt = td.t[i].d;
  int K = td.t[i].K, N = td.t[i].N;
  int lid = bid - td.base[i];
  int gx = N >> 5;
  int n0 = (lid % gx) * 32, k0 = (lid / gx) * 32;
  int tx = threadIdx.x & 31, ty = threadIdx.x >> 5;   // 32x8
#pragma unroll
  for (int j = 0; j < 32; j += 8)
    tile[ty + j][tx] = W[(size_t)(k0 + ty + j) * N + n0 + tx];
  __syncthreads();
#pragma unroll
  for (int j = 0; j < 32; j += 8)
    Wt[(size_t)(n0 + ty + j) * K + k0 + tx] = f32_to_bf16(tile[tx][ty + j]);
}

// ---------------- fused LayerNorm + time-shift mix (att) ----------------
__global__ __launch_bounds__(256) void lnmix_att(const float* __restrict__ x,
                                                 const float* __restrict__ g,
                                                 const float* __restrict__ bb,
                                                 const float* __restrict__ mk,
                                                 const float* __restrict__ mv,
                                                 const float* __restrict__ mr,
                                                 unsigned short* __restrict__ xk,
                                                 unsigned short* __restrict__ xv,
                                                 unsigned short* __restrict__ xr) {
  int row = blockIdx.x;
  int t = row & (LLEN - 1);
  int tid = threadIdx.x;
  float4 vc = ((const float4*)(x + (size_t)row * DSZ))[tid];
  float4 vp = make_float4(0.f, 0.f, 0.f, 0.f);
  if (t > 0) vp = ((const float4*)(x + (size_t)(row - 1) * DSZ))[tid];
  float sc = vc.x + vc.y + vc.z + vc.w;
  float qc = vc.x * vc.x + vc.y * vc.y + vc.z * vc.z + vc.w * vc.w;
  float sp = vp.x + vp.y + vp.z + vp.w;
  float qp = vp.x * vp.x + vp.y * vp.y + vp.z * vp.z + vp.w * vp.w;
#pragma unroll
  for (int off = 32; off; off >>= 1) {
    sc += __shfl_down(sc, off); qc += __shfl_down(qc, off);
    sp += __shfl_down(sp, off); qp += __shfl_down(qp, off);
  }
  __shared__ float red[16];
  int lane = tid & 63, w = tid >> 6;
  if (lane == 0) { red[w] = sc; red[4 + w] = qc; red[8 + w] = sp; red[12 + w] = qp; }
  __syncthreads();
  if (tid < 4) red[tid * 4] = red[tid * 4] + red[tid * 4 + 1] + red[tid * 4 + 2] + red[tid * 4 + 3];
  __syncthreads();
  const float invD = 1.f / DSZ;
  float mc = red[0] * invD, rc = rsqrtf(red[4] * invD - mc * mc + EPSLN);
  float mp = red[8] * invD, rp = rsqrtf(red[12] * invD - mp * mp + EPSLN);
  float4 G = ((const float4*)g)[tid], Bv = ((const float4*)bb)[tid];
  float c[4] = { vc.x, vc.y, vc.z, vc.w };
  float p[4] = { vp.x, vp.y, vp.z, vp.w };
  float Ga[4] = { G.x, G.y, G.z, G.w };
  float Ba[4] = { Bv.x, Bv.y, Bv.z, Bv.w };
  float4 K = ((const float4*)mk)[tid];
  float4 V = ((const float4*)mv)[tid];
  float4 R = ((const float4*)mr)[tid];
  float Ka[4] = { K.x, K.y, K.z, K.w };
  float Va[4] = { V.x, V.y, V.z, V.w };
  float Ra[4] = { R.x, R.y, R.z, R.w };
  ushort4 ok, ov, orr;
  unsigned short* okp = &ok.x; unsigned short* ovp = &ov.x; unsigned short* orp = &orr.x;
#pragma unroll
  for (int e = 0; e < 4; ++e) {
    float hc = (c[e] - mc) * rc * Ga[e] + Ba[e];
    float hp = (t > 0) ? (p[e] - mp) * rp * Ga[e] + Ba[e] : 0.f;
    okp[e] = f32_to_bf16(hc * Ka[e] + hp * (1.f - Ka[e]));
    ovp[e] = f32_to_bf16(hc * Va[e] + hp * (1.f - Va[e]));
    orp[e] = f32_to_bf16(hc * Ra[e] + hp * (1.f - Ra[e]));
  }
  size_t e4 = (size_t)row * DSZ + tid * 4;
  *(ushort4*)(xk + e4) = ok;
  *(ushort4*)(xv + e4) = ov;
  *(ushort4*)(xr + e4) = orr;
}

// ---------------- fused LayerNorm + time-shift mix (ffn) ----------------
__global__ __launch_bounds__(256) void lnmix_ffn(const float* __restrict__ x,
                                                 const float* __restrict__ g,
                                                 const float* __restrict__ bb,
                                                 const float* __restrict__ mk,
                                                 const float* __restrict__ mr,
                                                 unsigned short* __restrict__ xk,
                                                 unsigned short* __restrict__ xr) {
  int row = blockIdx.x;
  int t = row & (LLEN - 1);
  int tid = threadIdx.x;
  float4 vc = ((const float4*)(x + (size_t)row * DSZ))[tid];
  float4 vp = make_float4(0.f, 0.f, 0.f, 0.f);
  if (t > 0) vp = ((const float4*)(x + (size_t)(row - 1) * DSZ))[tid];
  float sc = vc.x + vc.y + vc.z + vc.w;
  float qc = vc.x * vc.x + vc.y * vc.y + vc.z * vc.z + vc.w * vc.w;
  float sp = vp.x + vp.y + vp.z + vp.w;
  float qp = vp.x * vp.x + vp.y * vp.y + vp.z * vp.z + vp.w * vp.w;
#pragma unroll
  for (int off = 32; off; off >>= 1) {
    sc += __shfl_down(sc, off); qc += __shfl_down(qc, off);
    sp += __shfl_down(sp, off); qp += __shfl_down(qp, off);
  }
  __shared__ float red[16];
  int lane = tid & 63, w = tid >> 6;
  if (lane == 0) { red[w] = sc; red[4 + w] = qc; red[8 + w] = sp; red[12 + w] = qp; }
  __syncthreads();
  if (tid < 4) red[tid * 4] = red[tid * 4] + red[tid * 4 + 1] + red[tid * 4 + 2] + red[tid * 4 + 3];
  __syncthreads();
  const float invD = 1.f / DSZ;
  float mc = red[0] * invD, rc = rsqrtf(red[4] * invD - mc * mc + EPSLN);
  float mp = red[8] * invD, rp = rsqrtf(red[12] * invD - mp * mp + EPSLN);
  float4 G = ((const float4*)g)[tid], Bv = ((const float4*)bb)[tid];
  float c[4] = { vc.x, vc.y, vc.z, vc.w };
  float p[4] = { vp.x, vp.y, vp.z, vp.w };
  float Ga[4] = { G.x, G.y, G.z, G.w };
  float Ba[4] = { Bv.x, Bv.y, Bv.z, Bv.w };
  float4 K = ((const float4*)mk)[tid];
  float4 R = ((const float4*)mr)[tid];
  float Ka[4] = { K.x, K.y, K.z, K.w };
  float Ra[4] = { R.x, R.y, R.z, R.w };
  ushort4 ok, orr;
  unsigned short* okp = &ok.x; unsigned short* orp = &orr.x;
#pragma unroll
  for (int e = 0; e < 4; ++e) {
    float hc = (c[e] - mc) * rc * Ga[e] + Ba[e];
    float hp = (t > 0) ? (p[e] - mp) * rp * Ga[e] + Ba[e] : 0.f;
    okp[e] = f32_to_bf16(hc * Ka[e] + hp * (1.f - Ka[e]));
    orp[e] = f32_to_bf16(hc * Ra[e] + hp * (1.f - Ra[e]));
  }
  size_t e4 = (size_t)row * DSZ + tid * 4;
  *(ushort4*)(xk + e4) = ok;
  *(ushort4*)(xr + e4) = orr;
}

// ---------------- WKV chunked scan (2 channels per thread, C=64, fast-math) ----------------
__global__ __launch_bounds__(256) void wkv_pass1(const unsigned int* __restrict__ kk2,
                                                 const unsigned int* __restrict__ vv2,
                                                 const float* __restrict__ td,
                                                 float* __restrict__ sP,
                                                 float* __restrict__ sQ,
                                                 float* __restrict__ sO) {
  int gid = blockIdx.x * 256 + threadIdx.x;       // 0 .. WKV_STATES/2-1
  int d2 = gid & 511;
  int bc = gid >> 9;
  int c  = bc & (WKV_C - 1);
  int b  = bc >> 6;
  int d0 = d2 * 2;
  float w0 = -fexp(td[d0]), w1 = -fexp(td[d0 + 1]);
  size_t base = ((size_t)b * LLEN + (size_t)c * WKV_S) * 512 + d2;   // uint units
  float p0 = 0.f, q0 = 0.f, o0 = -1e38f;
  float p1 = 0.f, q1 = 0.f, o1 = -1e38f;
  unsigned int kc = kk2[base], vc = vv2[base];
  unsigned int kA = 0, vA = 0, kB = 0, vB = 0;
  if (WKV_S > 1) { kA = kk2[base + 512]; vA = vv2[base + 512]; }
  for (int t = 0; t < WKV_S; ++t) {
    if (t + 2 < WKV_S) {
      size_t nxt = base + (size_t)(t + 2) * 512;
      kB = kk2[nxt]; vB = vv2[nxt];
    } else { kB = 0; vB = 0; }
    {
      float kt = bf16_lo(kc), vt = bf16_lo(vc);
      float ow = o0 + w0;
      float no2 = fmaxf(ow, kt);
      float A2 = fexp(ow - no2), B2 = fexp(kt - no2);
      p0 = A2 * p0 + B2 * vt; q0 = A2 * q0 + B2; o0 = no2;
    }
    {
      float kt = bf16_hi(kc), vt = bf16_hi(vc);
      float ow = o1 + w1;
      float no2 = fmaxf(ow, kt);
      float A2 = fexp(ow - no2), B2 = fexp(kt - no2);
      p1 = A2 * p1 + B2 * vt; q1 = A2 * q1 + B2; o1 = no2;
    }
    kc = kA; vc = vA; kA = kB; vA = vB;
  }
  int sidx = (bc << 10) + d0;
  sP[sidx] = p0; sP[sidx + 1] = p1;
  sQ[sidx] = q0; sQ[sidx + 1] = q1;
  sO[sidx] = o0; sO[sidx + 1] = o1;
}

__global__ __launch_bounds__(256) void wkv_combine(const float* __restrict__ sP,
                                                   const float* __restrict__ sQ,
                                                   const float* __restrict__ sO,
                                                   const float* __restrict__ td,
                                                   float* __restrict__ pP,
                                                   float* __restrict__ pQ,
                                                   float* __restrict__ pO) {
  int gid = blockIdx.x * 256 + threadIdx.x;
  int d = gid & (DSZ - 1);
  int b = gid >> 10;
  float w = -fexp(td[d]);
  float Sw = (float)WKV_S * w;
  float p = 0.f, q = 0.f, o = -1e38f;
  for (int c = 0; c < WKV_C; ++c) {
    size_t idx = (((size_t)b * WKV_C + c) << 10) + d;
    pP[idx] = p; pQ[idx] = q; pO[idx] = o;
    float lp = sP[idx], lq = sQ[idx], lo = sO[idx];
    float oin = o + Sw;
    float no  = fmaxf(oin, lo);
    float Ai  = fexp(oin - no);
    float Al  = fexp(lo - no);
    p = Ai * p + Al * lp;
    q = Ai * q + Al * lq;
    o = no;
  }
}

__global__ __launch_bounds__(256) void wkv_pass3(const unsigned int* __restrict__ kk2,
                                                 const unsigned int* __restrict__ vv2,
                                                 const unsigned int* __restrict__ rr2,
                                                 const float* __restrict__ td,
                                                 const float* __restrict__ tf,
                                                 const float* __restrict__ pP,
                                                 const float* __restrict__ pQ,
                                                 const float* __restrict__ pO,
                                                 unsigned int* __restrict__ rw2) {
  int gid = blockIdx.x * 256 + threadIdx.x;
  int d2 = gid & 511;
  int bc = gid >> 9;
  int c  = bc & (WKV_C - 1);
  int b  = bc >> 6;
  int d0 = d2 * 2;
  float w0 = -fexp(td[d0]), w1 = -fexp(td[d0 + 1]);
  float u0 = tf[d0], u1 = tf[d0 + 1];
  int sidx = (bc << 10) + d0;
  float p0 = pP[sidx], q0 = pQ[sidx], o0 = pO[sidx];
  float p1 = pP[sidx + 1], q1 = pQ[sidx + 1], o1 = pO[sidx + 1];
  size_t base = ((size_t)b * LLEN + (size_t)c * WKV_S) * 512 + d2;
  unsigned int kc = kk2[base], vc = vv2[base], rc = rr2[base];
  unsigned int kA = 0, vA = 0, rA = 0, kB = 0, vB = 0, rB = 0;
  if (WKV_S > 1) { kA = kk2[base + 512]; vA = vv2[base + 512]; rA = rr2[base + 512]; }
  for (int t = 0; t < WKV_S; ++t) {
    if (t + 2 < WKV_S) {
      size_t nxt = base + (size_t)(t + 2) * 512;
      kB = kk2[nxt]; vB = vv2[nxt]; rB = rr2[nxt];
    } else { kB = 0; vB = 0; rB = 0; }
    float out0, out1;
    {
      float kt = bf16_lo(kc), vt = bf16_lo(vc);
      float uk = u0 + kt;
      float no = fmaxf(o0, uk);
      float A  = fexp(o0 - no), Bc = fexp(uk - no);
      out0 = (A * p0 + Bc * vt) * frcp(A * q0 + Bc);
      float ow = o0 + w0;
      float no2 = fmaxf(ow, kt);
      float A2 = fexp(ow - no2), B2 = fexp(kt - no2);
      p0 = A2 * p0 + B2 * vt; q0 = A2 * q0 + B2; o0 = no2;
    }
    {
      float kt = bf16_hi(kc), vt = bf16_hi(vc);
      float uk = u1 + kt;
      float no = fmaxf(o1, uk);
      float A  = fexp(o1 - no), Bc = fexp(uk - no);
      out1 = (A * p1 + Bc * vt) * frcp(A * q1 + Bc);
      float ow = o1 + w1;
      float no2 = fmaxf(ow, kt);
      float A2 = fexp(ow - no2), B2 = fexp(kt - no2);
      p1 = A2 * p1 + B2 * vt; q1 = A2 * q1 + B2; o1 = no2;
    }
    rw2[base + (size_t)t * 512] = pack_bf16(bf16_lo(rc) * out0, bf16_hi(rc) * out1);
    kc = kA; vc = vA; rc = rA; kA = kB; vA = vB; rA = rB;
  }
}

// ============ 256x256 bf16 MFMA GEMM, 2-phase overlapped (R12 proven): C = A * Bt^T ============
// 512 threads = 8 waves (2M x 4N), BK=64, LDS 128 KiB dbuf. 2 barriers per K-tile.
// ph1: read a03,b01,b23 (16); stage A0A1[t+1]->bufn; Q1 (waits 12, b23 drains under);
//      Q2; bar#1. ph2: read a47 (8); stage B0B1[t+2]->buf; Q3; Q4; vmcnt(4); bar#2.
// launch_bounds(512,1): occupancy is LDS-bound at 1 block/CU (8 waves = 2/SIMD needs
// only VGPR<=256), so the old 128-VGPR cap was pure allocator constraint with no
// occupancy benefit; relaxing gives scheduling headroom, cannot reduce occupancy.
#define KTILE_BODY(T)                                                             \
  {                                                                               \
    const int buf  = ((T) & 1) << 15;                                             \
    const int bufn = buf ^ 32768;                                                 \
    bh8 a03[4][2], a47[4][2], b01[2][2], b23[2][2];                               \
    /* ---- phase 1 ---- */                                                       \
    _Pragma("unroll")                                                             \
    for (int mi = 0; mi < 4; ++mi) {                                              \
      a03[mi][0] = *(const bh8*)(smA + buf + aRow + mi * 2048 + sw0);             \
      a03[mi][1] = *(const bh8*)(smA + buf + aRow + mi * 2048 + sw1);             \
    }                                                                             \
    _Pragma("unroll")                                                             \
    for (int nj = 0; nj < 2; ++nj) {                                              \
      b01[nj][0] = *(const bh8*)(smB + buf + bRow + nj * 2048 + sw0);             \
      b01[nj][1] = *(const bh8*)(smB + buf + bRow + nj * 2048 + sw1);             \
    }                                                                             \
    _Pragma("unroll")                                                             \
    for (int nj = 0; nj < 2; ++nj) {                                              \
      b23[nj][0] = *(const bh8*)(smB + buf + bRow + (nj + 2) * 2048 + sw0);       \
      b23[nj][1] = *(const bh8*)(smB + buf + bRow + (nj + 2) * 2048 + sw1);       \
    }                                                                             \
    if ((T) + 1 < nk) {                                                           \
      load_lds16(pA0  + 64, smA + bufn + ldsW);                                   \
      load_lds16(pA0b + 64, smA + bufn + 1024 + ldsW);                            \
      load_lds16(pA1  + 64, smA + bufn + 16384 + ldsW);                           \
      load_lds16(pA1b + 64, smA + bufn + 16384 + 1024 + ldsW);                    \
    }                                                                             \
    __builtin_amdgcn_s_setprio(1);                                                \
    _Pragma("unroll")                                                             \
    for (int mi = 0; mi < 4; ++mi)                                                \
      _Pragma("unroll")                                                           \
      for (int nj = 0; nj < 2; ++nj) {                                            \
        acc[mi][nj] = __builtin_amdgcn_mfma_f32_16x16x32_bf16(a03[mi][0], b01[nj][0], acc[mi][nj], 0, 0, 0); \
        acc[mi][nj] = __builtin_amdgcn_mfma_f32_16x16x32_bf16(a03[mi][1], b01[nj][1], acc[mi][nj], 0, 0, 0); \
      }                                                                           \
    _Pragma("unroll")                                                             \
    for (int mi = 0; mi < 4; ++mi)                                                \
      _Pragma("unroll")                                                           \
      for (int nj = 0; nj < 2; ++nj) {                                            \
        acc[mi][nj + 2] = __builtin_amdgcn_mfma_f32_16x16x32_bf16(a03[mi][0], b23[nj][0], acc[mi][nj + 2], 0, 0, 0); \
        acc[mi][nj + 2] = __builtin_amdgcn_mfma_f32_16x16x32_bf16(a03[mi][1], b23[nj][1], acc[mi][nj + 2], 0, 0, 0); \
      }                                                                           \
    __builtin_amdgcn_s_setprio(0);                                                \
    RAW_BAR();                                                                    \
    /* ---- phase 2 ---- */                                                       \
    _Pragma("unroll")                                                             \
    for (int mi = 0; mi < 4; ++mi) {                                              \
      a47[mi][0] = *(const bh8*)(smA + buf + aRow + (mi + 4) * 2048 + sw0);       \
      a47[mi][1] = *(const bh8*)(smA + buf + aRow + (mi + 4) * 2048 + sw1);       \
    }                                                                             \
    if ((T) + 2 < nk) {                                                           \
      load_lds16(pB0  + 128, smB + buf + ldsW);                                   \
      load_lds16(pB0b + 128, smB + buf + 1024 + ldsW);                            \
      load_lds16(pB1  + 128, smB + buf + 16384 + ldsW);                           \
      load_lds16(pB1b + 128, smB + buf + 16384 + 1024 + ldsW);                    \
    }                                                                             \
    __builtin_amdgcn_s_setprio(1);                                                \
    _Pragma("unroll")                                                             \
    for (int mi = 0; mi < 4; ++mi)                                                \
      _Pragma("unroll")                                                           \
      for (int nj = 0; nj < 2; ++nj) {                                            \
        acc[mi + 4][nj] = __builtin_amdgcn_mfma_f32_16x16x32_bf16(a47[mi][0], b01[nj][0], acc[mi + 4][nj], 0, 0, 0); \
        acc[mi + 4][nj] = __builtin_amdgcn_mfma_f32_16x16x32_bf16(a47[mi][1], b01[nj][1], acc[mi + 4][nj], 0, 0, 0); \
      }                                                                           \
    _Pragma("unroll")                                                             \
    for (int mi = 0; mi < 4; ++mi)                                                \
      _Pragma("unroll")                                                           \
      for (int nj = 0; nj < 2; ++nj) {                                            \
        acc[mi + 4][nj + 2] = __builtin_amdgcn_mfma_f32_16x16x32_bf16(a47[mi][0], b23[nj][0], acc[mi + 4][nj + 2], 0, 0, 0); \
        acc[mi + 4][nj + 2] = __builtin_amdgcn_mfma_f32_16x16x32_bf16(a47[mi][1], b23[nj][1], acc[mi + 4][nj + 2], 0, 0, 0); \
      }                                                                           \
    __builtin_amdgcn_s_setprio(0);                                                \
    if ((T) + 2 < nk) { WAIT_VM4(); } else { WAIT_VM0(); }                        \
    RAW_BAR();                                                                    \
  }

// common body: setup + prologue + K-loop
#define GEMM_SETUP(AB, BB_, KD)                                                   \
  const unsigned short* Ab = (AB);                                                \
  const unsigned short* Bb = (BB_);                                               \
  const int nk = (KD) >> 6;                                                       \
  const int r15 = lane & 15;                                                      \
  const int sw0 = ((((lane >> 4)    ) ^ (lane & 7)) << 4);                        \
  const int sw1 = (((4 | (lane >> 4)) ^ (lane & 7)) << 4);                        \
  const int aRow = wr * 16384 + r15 * 128;                                        \
  const int bRow = wc * 8192  + r15 * 128;                                        \
  const int ldsW = wid * 2048 + lane * 16;                                        \
  const int grow = lane >> 3;                                                     \
  const int colS = (((lane & 7) ^ grow) << 3);                                    \
  const unsigned short* pA0  = Ab + (size_t)(wid * 16 + grow) * (KD) + colS;      \
  const unsigned short* pA0b = pA0 + (size_t)8 * (KD);                            \
  const unsigned short* pA1  = pA0 + (size_t)128 * (KD);                          \
  const unsigned short* pA1b = pA1 + (size_t)8 * (KD);                            \
  const unsigned short* pB0  = Bb + (size_t)(wid * 16 + grow) * (KD) + colS;      \
  const unsigned short* pB0b = pB0 + (size_t)8 * (KD);                            \
  const unsigned short* pB1  = pB0 + (size_t)128 * (KD);                          \
  const unsigned short* pB1b = pB1 + (size_t)8 * (KD);                            \
  f32x4 acc[8][4];                                                                \
  _Pragma("unroll")                                                               \
  for (int i = 0; i < 8; ++i)                                                     \
    _Pragma("unroll")                                                             \
    for (int j = 0; j < 4; ++j)                                                   \
      _Pragma("unroll")                                                           \
      for (int e = 0; e < 4; ++e) acc[i][j][e] = 0.f;                             \
  /* prologue: tile0 A+B (8 loads), then B[1] (4); vmcnt(4) retires tile0 */      \
  load_lds16(pA0,       smA + ldsW);                                              \
  load_lds16(pA0b,      smA + 1024 + ldsW);                                       \
  load_lds16(pA1,       smA + 16384 + ldsW);                                      \
  load_lds16(pA1b,      smA + 16384 + 1024 + ldsW);                               \
  load_lds16(pB0,       smB + ldsW);                                              \
  load_lds16(pB0b,      smB + 1024 + ldsW);                                       \
  load_lds16(pB1,       smB + 16384 + ldsW);                                      \
  load_lds16(pB1b,      smB + 16384 + 1024 + ldsW);                               \
  if (nk > 1) {                                                                   \
    load_lds16(pB0  + 64, smB + 32768 + ldsW);                                    \
    load_lds16(pB0b + 64, smB + 32768 + 1024 + ldsW);                             \
    load_lds16(pB1  + 64, smB + 32768 + 16384 + ldsW);                            \
    load_lds16(pB1b + 64, smB + 32768 + 16384 + 1024 + ldsW);                     \
    WAIT_VM4();                                                                   \
  } else {                                                                        \
    WAIT_VM0();                                                                   \
  }                                                                               \
  RAW_BAR();                                                                      \
  for (int tb = 0; tb < nk; ++tb) {                                               \
    KTILE_BODY(tb)                                                                \
    pA0 += 64; pA0b += 64; pA1 += 64; pA1b += 64;                                 \
    pB0 += 64; pB0b += 64; pB1 += 64; pB1b += 64;                                 \
  }

template <int EPI>
__global__ __launch_bounds__(512, 1) void gemm256(const unsigned short* __restrict__ A,
                                                  const unsigned short* __restrict__ Bt,
                                                  float* __restrict__ C,
                                                  unsigned short* __restrict__ Cbf,
                                                  const float* __restrict__ aux1,
                                                  const unsigned short* __restrict__ aux2b,
                                                  int M, int N, int K) {
  extern __shared__ unsigned char sm[];            // 131072 bytes
  unsigned char* smA = sm;
  unsigned char* smB = sm + 65536;
  const int tid  = threadIdx.x;
  const int lane = tid & 63;
  const int wid  = tid >> 6;
  const int wr   = wid >> 2;
  const int wc   = wid & 3;
  int nwg = gridDim.x;
  int gx  = N >> 8;
  int wg  = blockIdx.x;
  int swzid = ((nwg & 7) == 0) ? ((wg & 7) * (nwg >> 3) + (wg >> 3)) : wg;
  int bn = swzid % gx, bm = swzid / gx;

  GEMM_SETUP(A + (size_t)bm * 256 * K, Bt + (size_t)bn * 256 * K, K)

  const int r4 = (lane >> 4) * 4, cn = lane & 15;
#pragma unroll
  for (int mi = 0; mi < 8; ++mi) {
#pragma unroll
    for (int nj = 0; nj < 4; ++nj) {
      int col = bn * 256 + wc * 64 + nj * 16 + cn;
#pragma unroll
      for (int e = 0; e < 4; ++e) {
        int row = bm * 256 + wr * 128 + mi * 16 + r4 + e;
        size_t idx = (size_t)row * N + col;
        float val = acc[mi][nj][e];
        if (EPI == 0) {
          Cbf[idx] = f32_to_bf16(val);
        } else if (EPI == 1) {
          Cbf[idx] = f32_to_bf16(frcp(1.f + fexp(-val)));
        } else if (EPI == 2) {
          C[idx] = aux1[idx] + val;
        } else if (EPI == 3) {
          float tt = val > 0.f ? val : 0.f;
          Cbf[idx] = f32_to_bf16(tt * tt);
        } else {
          C[idx] = aux1[idx] + bf16_to_f32(aux2b[idx]) * val;
        }
      }
    }
  }
}

// batched k/v/r projection: 3 independent M=16384 N=1024 K=1024 GEMMs in one launch.
__global__ __launch_bounds__(512, 1) void gemm256_kvr(const unsigned short* __restrict__ A0,
                                                      const unsigned short* __restrict__ A1,
                                                      const unsigned short* __restrict__ A2,
                                                      const unsigned short* __restrict__ B0w,
                                                      const unsigned short* __restrict__ B1w,
                                                      const unsigned short* __restrict__ B2w,
                                                      unsigned short* __restrict__ D0,
                                                      unsigned short* __restrict__ D1,
                                                      unsigned short* __restrict__ D2) {
  extern __shared__ unsigned char sm[];
  unsigned char* smA = sm;
  unsigned char* smB = sm + 65536;
  const int tid  = threadIdx.x;
  const int lane = tid & 63;
  const int wid  = tid >> 6;
  const int wr   = wid >> 2;
  const int wc   = wid & 3;
  int nwg = gridDim.x;                             // 768, %8==0
  int wg  = blockIdx.x;
  int swzid = (wg & 7) * (nwg >> 3) + (wg >> 3);
  int gsel  = swzid >> 8;                          // 0..2
  int local = swzid & 255;
  int bn = local & 3, bm = local >> 2;

  const unsigned short* Asel = (gsel == 0) ? A0 : (gsel == 1) ? A1 : A2;
  const unsigned short* Bsel = (gsel == 0) ? B0w : (gsel == 1) ? B1w : B2w;
  unsigned short*       Dsel = (gsel == 0) ? D0 : (gsel == 1) ? D1 : D2;

  GEMM_SETUP(Asel + (size_t)bm * 256 * DSZ, Bsel + (size_t)bn * 256 * DSZ, DSZ)

  const int r4 = (lane >> 4) * 4, cn = lane & 15;
  const bool sig = (gsel == 2);
#pragma unroll
  for (int mi = 0; mi < 8; ++mi) {
#pragma unroll
    for (int nj = 0; nj < 4; ++nj) {
      int col = bn * 256 + wc * 64 + nj * 16 + cn;
#pragma unroll
      for (int e = 0; e < 4; ++e) {
        int row = bm * 256 + wr * 128 + mi * 16 + r4 + e;
        size_t idx = (size_t)row * DSZ + col;
        float val = acc[mi][nj][e];
        Dsel[idx] = f32_to_bf16(sig ? frcp(1.f + fexp(-val)) : val);
      }
    }
  }
}

// ---------------- host launcher ----------------
extern "C" void kernel_launch(void* const* d_in, const int* in_sizes, int n_in,
                              void* d_out, int out_size, void* d_ws, size_t ws_size,
                              hipStream_t stream) {
  const float* x        = (const float*)d_in[0];
  const float* ln_att_g = (const float*)d_in[1];
  const float* ln_att_b = (const float*)d_in[2];
  const float* ln_ffn_g = (const float*)d_in[3];
  const float* ln_ffn_b = (const float*)d_in[4];
  const float* td       = (const float*)d_in[5];
  const float* tf       = (const float*)d_in[6];
  const float* amk      = (const float*)d_in[7];
  const float* amv      = (const float*)d_in[8];
  const float* amr      = (const float*)d_in[9];
  const float* att_wk   = (const float*)d_in[10];
  const float* att_wv   = (const float*)d_in[11];
  const float* att_wr   = (const float*)d_in[12];
  const float* att_wo   = (const float*)d_in[13];
  const float* fmk      = (const float*)d_in[14];
  const float* fmr      = (const float*)d_in[15];
  const float* ffn_wk   = (const float*)d_in[16];
  const float* ffn_wv   = (const float*)d_in[17];
  const float* ffn_wr   = (const float*)d_in[18];
  float* out = (float*)d_out;
  (void)in_sizes; (void)n_in; (void)out_size;

  const size_t WBYTES  = 4 * ((size_t)DSZ * DSZ * 2)
                       + (size_t)FFN * DSZ * 2
                       + (size_t)DSZ * FFN * 2
                       + (size_t)DSZ * DSZ * 2;
  const size_t BUF     = (size_t)MROWS * DSZ * 2;
  const size_t NEEDED  = WBYTES + 4 * BUF + 2 * BUF;
  if (ws_size < NEEDED) return;

  char* ws = (char*)d_ws;
  size_t off = 0;
  auto take = [&](size_t bytes) { char* p = ws + off; off += (bytes + 255) & ~(size_t)255; return p; };

  unsigned short* wkT  = (unsigned short*)take((size_t)DSZ * DSZ * 2);
  unsigned short* wvT  = (unsigned short*)take((size_t)DSZ * DSZ * 2);
  unsigned short* wrT  = (unsigned short*)take((size_t)DSZ * DSZ * 2);
  unsigned short* woT  = (unsigned short*)take((size_t)DSZ * DSZ * 2);
  unsigned short* fwkT = (unsigned short*)take((size_t)FFN * DSZ * 2);
  unsigned short* fwvT = (unsigned short*)take((size_t)DSZ * FFN * 2);
  unsigned short* fwrT = (unsigned short*)take((size_t)DSZ * DSZ * 2);
  unsigned short* bufA = (unsigned short*)take(BUF);
  unsigned short* bufB = (unsigned short*)take(BUF);
  unsigned short* bufC = (unsigned short*)take(BUF);
  unsigned short* bufD = (unsigned short*)take(BUF);
  char*           eReg = take(2 * BUF);
  unsigned short* kf = bufC;                       // spans C + D + E (ffn phase)
  unsigned short* vBuf = (unsigned short*)eReg;            // E[0:32M)  (att phase)
  unsigned short* rBuf = (unsigned short*)(eReg + BUF);    // E[32M:64M)

  // WKV state arrays live in bufA (xk dead after kvr GEMM): 6 x 2 MB
  float* sP = (float*)bufA;
  float* sQ = sP + WKV_STATES;
  float* sO = sQ + WKV_STATES;
  float* pP = sO + WKV_STATES;
  float* pQ = pP + WKV_STATES;
  float* pO = pQ + WKV_STATES;

  // ---- single merged transpose launch (7 matrices) ----
  TDs tds;
  tds.t[0] = { att_wk, wkT,  DSZ, DSZ };
  tds.t[1] = { att_wv, wvT,  DSZ, DSZ };
  tds.t[2] = { att_wr, wrT,  DSZ, DSZ };
  tds.t[3] = { att_wo, woT,  DSZ, DSZ };
  tds.t[4] = { ffn_wr, fwrT, DSZ, DSZ };
  tds.t[5] = { ffn_wk, fwkT, DSZ, FFN };
  tds.t[6] = { ffn_wv, fwvT, FFN, DSZ };
  int acc = 0;
  for (int i = 0; i < 7; ++i) {
    tds.base[i] = acc;
    acc += (tds.t[i].N >> 5) * (tds.t[i].K >> 5);
  }
  tds.base[7] = acc;                               // 13312
  transpose_all<<<acc, 256, 0, stream>>>(tds);

  const int LDSB = 131072;
  const int G1   = (MROWS / 256) * (DSZ / 256);    // 256 blocks
  const int G2   = (MROWS / 256) * (FFN / 256);    // 1024 blocks

  // --- attention branch ---
  lnmix_att<<<MROWS, 256, 0, stream>>>(x, ln_att_g, ln_att_b, amk, amv, amr, bufA, bufB, bufC);
  gemm256_kvr<<<3 * G1, 512, LDSB, stream>>>(bufA, bufB, bufC, wkT, wvT, wrT, bufD, vBuf, rBuf);
  wkv_pass1<<<(WKV_STATES / 2) / 256, 256, 0, stream>>>((const unsigned int*)bufD, (const unsigned int*)vBuf, td, sP, sQ, sO);
  wkv_combine<<<(BB * DSZ) / 256, 256, 0, stream>>>(sP, sQ, sO, td, pP, pQ, pO);
  wkv_pass3<<<(WKV_STATES / 2) / 256, 256, 0, stream>>>((const unsigned int*)bufD, (const unsigned int*)vBuf, (const unsigned int*)rBuf, td, tf, pP, pQ, pO, (unsigned int*)bufB);
  gemm256<2><<<G1, 512, LDSB, stream>>>(bufB, woT, out, nullptr, x, nullptr, MROWS, DSZ, DSZ);

  // --- ffn branch ---
  lnmix_ffn<<<MROWS, 256, 0, stream>>>(out, ln_ffn_g, ln_ffn_b, fmk, fmr, bufA, bufB);
  gemm256<3><<<G2, 512, LDSB, stream>>>(bufA, fwkT, nullptr, kf, nullptr, nullptr, MROWS, FFN, DSZ);
  gemm256<1><<<G1, 512, LDSB, stream>>>(bufB, fwrT, nullptr, bufA, nullptr, nullptr, MROWS, DSZ, DSZ);
  gemm256<4><<<G1, 512, LDSB, stream>>>(kf, fwvT, out, nullptr, out, bufA, MROWS, DSZ, FFN);
}